// Round 5
// baseline (4640.105 us; speedup 1.0000x reference)
//
#include <hip/hip_runtime.h>

#define N_NODES  50000
#define NPAD     50048          // 782 * 64
#define IN_F     128
#define OUT_F    128
#define N_REL    8
#define N_BASES  4
#define N_EDGES  800000
#define E4       (N_EDGES / 4)  // 200000
#define KTOT     (N_REL * IN_F) // 1024
#define NBIN     782            // ceil(NPAD/64) bins of 64 nodes per relation
#define BIN_NODES 64
#define BINCAP   1536           // Poisson(1024), sigma 32 -> 16 sigma headroom
#define CAP      64             // fallback per-node bucket cap

typedef unsigned short ushort_t;
typedef __attribute__((ext_vector_type(8))) short short8;
typedef __attribute__((ext_vector_type(4))) float f32x4;
typedef __attribute__((ext_vector_type(4))) int  int4v;

__device__ inline ushort_t f2bf(float f) {
    unsigned u = __float_as_uint(f);
    return (ushort_t)((u + 0x7fffu + ((u >> 16) & 1u)) >> 16);   // RNE
}
__device__ inline float bflo(unsigned v) { return __uint_as_float(v << 16); }
__device__ inline float bfhi(unsigned v) { return __uint_as_float(v & 0xffff0000u); }

// BT[o][r*128+i] = sum_b w_comp[r,b]*weight[b,i,o]  (bf16, B^T layout for MFMA)
__global__ __launch_bounds__(256) void compute_ws_bt_kernel(
    const float* __restrict__ weight,
    const float* __restrict__ w_comp,
    ushort_t* __restrict__ BT)
{
    int idx = blockIdx.x * 256 + threadIdx.x;        // over 128*1024
    if (idx >= OUT_F * KTOT) return;
    int o  = idx >> 10;
    int ri = idx & 1023;
    int r  = ri >> 7;
    int i  = ri & 127;
    float acc = 0.f;
#pragma unroll
    for (int b = 0; b < N_BASES; ++b)
        acc += w_comp[r * N_BASES + b] * weight[b * (IN_F * OUT_F) + i * OUT_F + o];
    BT[idx] = f2bf(acc);
}

// xb[node][j] packs bf16(x[node][j]) | bf16(x[node][j+64])<<16  for j in 0..63.
// This packing makes the LDS ds_add_f32 in bin_agg 2-lanes/bank (conflict-free).
__global__ __launch_bounds__(256) void x2bf_kernel(
    const float* __restrict__ x, unsigned* __restrict__ xb)
{
    int i = blockIdx.x * 256 + threadIdx.x;          // over N*64
    if (i >= N_NODES * 64) return;
    int node = i >> 6, j = i & 63;
    float lo = x[(size_t)node * IN_F + j];
    float hi = x[(size_t)node * IN_F + j + 64];
    xb[i] = (unsigned)f2bf(lo) | ((unsigned)f2bf(hi) << 16);
}

// Phase A: coarse binning. bin = (r, dst>>6). Hot line set = 6256 x 64B
// = 400 KB -> L2-resident everywhere; entries write-combine into full lines.
// Edge reads are non-temporal so the 51 MB stream doesn't evict bin lines.
// bcnt padded to 1 counter per 64B line (no same-line atomic serialization).
__global__ __launch_bounds__(256) void bin_fill_kernel(
    const int4v* __restrict__ src4,
    const int4v* __restrict__ dst4,
    int* __restrict__ bcnt,            // stride 16 ints per bin
    unsigned* __restrict__ binbuf)
{
    int r  = blockIdx.x & 7;
    int cb = blockIdx.x >> 3;                         // 0..255
    const int4v* s4 = src4 + (size_t)r * E4;
    const int4v* d4 = dst4 + (size_t)r * E4;
    int bin0 = r * NBIN;
    for (int i4 = cb * 256 + (int)threadIdx.x; i4 < E4; i4 += 256 * 256) {
        int4v s = __builtin_nontemporal_load(&s4[i4]);
        int4v d = __builtin_nontemporal_load(&d4[i4]);
#define PUT(DV, SV) { int b = bin0 + ((DV) >> 6);                             \
        int pos = atomicAdd(&bcnt[b * 16], 1);                                \
        if (pos < BINCAP)                                                     \
            binbuf[(size_t)b * BINCAP + pos] =                                \
                (unsigned)(SV) | ((unsigned)((DV) & 63) << 16); }
        PUT(d.x, s.x) PUT(d.y, s.y) PUT(d.z, s.z) PUT(d.w, s.w)
#undef PUT
    }
}

// Phase B: one block per (r, bin). 64-node x 128-feat f32 accumulator in LDS.
// Scan bin's edge list, shfl-broadcast 4 edges at a time (4-deep MLP on the
// 256B x-row loads), ds_add_f32 accumulate, then mean -> bf16 -> A.
__global__ __launch_bounds__(256) void bin_agg_kernel(
    const unsigned* __restrict__ xb,
    const int* __restrict__ bcnt,
    const unsigned* __restrict__ binbuf,
    ushort_t* __restrict__ A)          // [NPAD][KTOT]
{
    __shared__ float agg[BIN_NODES][IN_F];    // 32 KB
    __shared__ int   deg[BIN_NODES];

    int r   = blockIdx.x & 7;
    int bin = blockIdx.x >> 3;                // 0..781
    int gb  = r * NBIN + bin;
    int t = threadIdx.x;

    for (int i = t; i < BIN_NODES * IN_F; i += 256) ((float*)agg)[i] = 0.f;
    if (t < BIN_NODES) deg[t] = 0;
    __syncthreads();

    int cnt = min(bcnt[gb * 16], BINCAP);
    const unsigned* eb = binbuf + (size_t)gb * BINCAP;
    int wv = t >> 6, lane = t & 63;

    for (int base = wv * 64; base < cnt; base += 256) {
        int m = min(cnt - base, 64);
        unsigned entry = (lane < m) ? __builtin_nontemporal_load(&eb[base + lane]) : 0u;
        int j = 0;
        for (; j + 4 <= m; j += 4) {
            unsigned e0 = __shfl(entry, j + 0);
            unsigned e1 = __shfl(entry, j + 1);
            unsigned e2 = __shfl(entry, j + 2);
            unsigned e3 = __shfl(entry, j + 3);
            unsigned v0 = xb[(size_t)(e0 & 0xFFFFu) * 64 + lane];
            unsigned v1 = xb[(size_t)(e1 & 0xFFFFu) * 64 + lane];
            unsigned v2 = xb[(size_t)(e2 & 0xFFFFu) * 64 + lane];
            unsigned v3 = xb[(size_t)(e3 & 0xFFFFu) * 64 + lane];
            int d0 = e0 >> 16, d1 = e1 >> 16, d2 = e2 >> 16, d3 = e3 >> 16;
            atomicAdd(&agg[d0][lane],      bflo(v0));
            atomicAdd(&agg[d0][lane + 64], bfhi(v0));
            atomicAdd(&agg[d1][lane],      bflo(v1));
            atomicAdd(&agg[d1][lane + 64], bfhi(v1));
            atomicAdd(&agg[d2][lane],      bflo(v2));
            atomicAdd(&agg[d2][lane + 64], bfhi(v2));
            atomicAdd(&agg[d3][lane],      bflo(v3));
            atomicAdd(&agg[d3][lane + 64], bfhi(v3));
            if (lane == 0) {
                atomicAdd(&deg[d0], 1); atomicAdd(&deg[d1], 1);
                atomicAdd(&deg[d2], 1); atomicAdd(&deg[d3], 1);
            }
        }
        for (; j < m; ++j) {
            unsigned e0 = __shfl(entry, j);
            unsigned v0 = xb[(size_t)(e0 & 0xFFFFu) * 64 + lane];
            int d0 = e0 >> 16;
            atomicAdd(&agg[d0][lane],      bflo(v0));
            atomicAdd(&agg[d0][lane + 64], bfhi(v0));
            if (lane == 0) atomicAdd(&deg[d0], 1);
        }
    }
    __syncthreads();

    int node0 = bin * BIN_NODES;
    for (int idx = t; idx < BIN_NODES * 64; idx += 256) {
        int n  = idx >> 6, dw = idx & 63;
        int gn = node0 + n;
        if (gn >= N_NODES) continue;
        float inv = 1.0f / fmaxf((float)deg[n], 1.0f);
        unsigned lo = f2bf(agg[n][dw * 2]     * inv);
        unsigned hi = f2bf(agg[n][dw * 2 + 1] * inv);
        __builtin_nontemporal_store(lo | (hi << 16),
            (unsigned*)(A + (size_t)gn * KTOT + r * IN_F) + dw);
    }
}

// ---------------- fallback-path kernels (small workspace) ----------------
__global__ __launch_bounds__(256) void bucket_fill_kernel(
    const int* __restrict__ src,
    const int* __restrict__ dst,
    int* __restrict__ cnt,
    ushort_t* __restrict__ bucket,
    int nedges)
{
    int e = blockIdx.x * 256 + threadIdx.x;
    if (e >= nedges) return;
    int d = dst[e];
    int pos = atomicAdd(&cnt[d], 1);
    if (pos < CAP)
        bucket[(size_t)d * CAP + pos] = (ushort_t)src[e];
}

__global__ __launch_bounds__(256) void gather_mean_fb_kernel(
    const float* __restrict__ x,
    const int* __restrict__ cnt,
    const ushort_t* __restrict__ bucket,
    ushort_t* __restrict__ A)
{
    int wv = (blockIdx.x * 256 + threadIdx.x) >> 6;
    if (wv >= N_NODES) return;
    int lane = threadIdx.x & 63;
    int c  = cnt[wv];
    int cc = min(c, CAP);
    int sid = (lane < cc) ? (int)bucket[(size_t)wv * CAP + lane] : 0;

    float ax = 0.f, ay = 0.f, bx = 0.f, by = 0.f;
    int e = 0;
    for (; e + 2 <= cc; e += 2) {
        int s0 = __shfl(sid, e);
        int s1 = __shfl(sid, e + 1);
        const float2 v0 = *(const float2*)(x + (size_t)s0 * IN_F + lane * 2);
        const float2 v1 = *(const float2*)(x + (size_t)s1 * IN_F + lane * 2);
        ax += v0.x; ay += v0.y;
        bx += v1.x; by += v1.y;
    }
    if (e < cc) {
        int s0 = __shfl(sid, e);
        const float2 v0 = *(const float2*)(x + (size_t)s0 * IN_F + lane * 2);
        ax += v0.x; ay += v0.y;
    }
    const float inv = 1.0f / fmaxf((float)c, 1.0f);
    unsigned lo = f2bf((ax + bx) * inv);
    unsigned hi = f2bf((ay + by) * inv);
    ((unsigned*)(A + (size_t)wv * IN_F))[lane] = lo | (hi << 16);
}

// C[rows x 128] (+)= A[rows x K]_bf16 @ B (BT stored [128][KTOT]).
// Block 256 = 4 waves; block tile 64 rows x 128 cols; wave = 32 rows x 64 cols.
__global__ __launch_bounds__(256) void gemm_mfma_kernel(
    const ushort_t* __restrict__ A, int lda,
    const ushort_t* __restrict__ BT, int kbase, int K,
    float* __restrict__ out, const float* __restrict__ bias,
    int first, int last)
{
    int tid  = threadIdx.x;
    int wave = tid >> 6, lane = tid & 63;
    int rowf = lane & 15, kg = lane >> 4;
    int rbase = blockIdx.x * 64 + (wave & 1) * 32;
    int cbase = (wave >> 1) * 64;

    f32x4 acc[2][4];
#pragma unroll
    for (int t = 0; t < 2; ++t)
#pragma unroll
        for (int c = 0; c < 4; ++c) acc[t][c] = (f32x4){0.f, 0.f, 0.f, 0.f};

    const ushort_t* Arow0 = A + (size_t)(rbase + rowf) * lda;
    const ushort_t* Arow1 = A + (size_t)(rbase + 16 + rowf) * lda;
    const ushort_t* Bbase = BT + (size_t)(cbase + rowf) * KTOT + kbase;

    for (int k0 = 0; k0 < K; k0 += 32) {
        int kk = k0 + kg * 8;
        short8 a0 = *(const short8*)(Arow0 + kk);
        short8 a1 = *(const short8*)(Arow1 + kk);
#pragma unroll
        for (int c = 0; c < 4; ++c) {
            short8 b = *(const short8*)(Bbase + c * 16 * KTOT + kk);
            acc[0][c] = __builtin_amdgcn_mfma_f32_16x16x32_bf16(a0, b, acc[0][c], 0, 0, 0);
            acc[1][c] = __builtin_amdgcn_mfma_f32_16x16x32_bf16(a1, b, acc[1][c], 0, 0, 0);
        }
    }

    // C/D layout: col = lane&15, row = (lane>>4)*4 + j
#pragma unroll
    for (int t = 0; t < 2; ++t) {
#pragma unroll
        for (int c = 0; c < 4; ++c) {
            int col = cbase + c * 16 + rowf;
#pragma unroll
            for (int j = 0; j < 4; ++j) {
                int row = rbase + t * 16 + kg * 4 + j;
                if (row < N_NODES) {
                    float v = acc[t][c][j];
                    float* p = out + (size_t)row * OUT_F + col;
                    if (!first) v += *p;
                    if (last)  v = fmaxf(v + bias[col], 0.f);
                    *p = v;
                }
            }
        }
    }
}

extern "C" void kernel_launch(void* const* d_in, const int* in_sizes, int n_in,
                              void* d_out, int out_size, void* d_ws, size_t ws_size,
                              hipStream_t stream) {
    const float* x      = (const float*)d_in[0];
    const float* weight = (const float*)d_in[1];
    const float* w_comp = (const float*)d_in[2];
    const float* h_bias = (const float*)d_in[3];
    const int*   src    = (const int*)d_in[4];
    const int*   dst    = (const int*)d_in[5];
    float* out = (float*)d_out;

    char* wsb = (char*)d_ws;
    const size_t btSz  = (size_t)OUT_F * KTOT * 2;                  // 256 KB
    const size_t bcSz  = (size_t)N_REL * NBIN * 16 * 4;             // 400 KB (padded counters)
    const size_t bbSz  = (size_t)N_REL * NBIN * BINCAP * 4;         // 38.4 MB
    const size_t aSz   = (size_t)NPAD * KTOT * 2;                   // 102.5 MB
    const size_t xbSz  = (size_t)N_NODES * 64 * 4;                  // 12.8 MB
    const size_t need  = btSz + bcSz + bbSz + aSz + xbSz;           // ~154.4 MB

    ushort_t* BT = (ushort_t*)wsb;
    compute_ws_bt_kernel<<<(OUT_F * KTOT + 255) / 256, 256, 0, stream>>>(
        weight, w_comp, BT);

    if (ws_size >= need) {
        int*      bcnt   = (int*)(wsb + btSz);
        unsigned* binbuf = (unsigned*)(wsb + btSz + bcSz);
        ushort_t* A      = (ushort_t*)(wsb + btSz + bcSz + bbSz);
        unsigned* xb     = (unsigned*)(wsb + btSz + bcSz + bbSz + aSz);

        x2bf_kernel<<<(N_NODES * 64 + 255) / 256, 256, 0, stream>>>(x, xb);
        hipMemsetAsync(bcnt, 0, bcSz, stream);
        bin_fill_kernel<<<8 * 256, 256, 0, stream>>>(
            (const int4v*)src, (const int4v*)dst, bcnt, binbuf);
        bin_agg_kernel<<<N_REL * NBIN, 256, 0, stream>>>(xb, bcnt, binbuf, A);
        gemm_mfma_kernel<<<NPAD / 64, 256, 0, stream>>>(
            A, KTOT, BT, 0, KTOT, out, h_bias, 1, 1);
    } else {
        // per-relation fallback (~19.7 MB)
        const size_t cntSz1 = (size_t)N_NODES * 4;
        const size_t bktSz1 = (size_t)N_NODES * CAP * 2;
        int*      cnt    = (int*)(wsb + btSz);
        ushort_t* bucket = (ushort_t*)(wsb + btSz + cntSz1);
        ushort_t* A      = (ushort_t*)(wsb + btSz + cntSz1 + bktSz1);

        for (int r = 0; r < N_REL; ++r) {
            hipMemsetAsync(cnt, 0, cntSz1, stream);
            bucket_fill_kernel<<<(N_EDGES + 255) / 256, 256, 0, stream>>>(
                src + (size_t)r * N_EDGES, dst + (size_t)r * N_EDGES,
                cnt, bucket, N_EDGES);
            gather_mean_fb_kernel<<<(N_NODES * 64 + 255) / 256, 256, 0, stream>>>(
                x, cnt, bucket, A);
            gemm_mfma_kernel<<<NPAD / 64, 256, 0, stream>>>(
                A, IN_F, BT, r * IN_F, IN_F, out, h_bias,
                r == 0, r == N_REL - 1);
        }
    }
}

// Round 6
// 880.256 us; speedup vs baseline: 5.2713x; 5.2713x over previous
//
#include <hip/hip_runtime.h>

#define N_NODES  50000
#define NPAD     50048          // 782 * 64
#define IN_F     128
#define OUT_F    128
#define N_REL    8
#define N_BASES  4
#define N_EDGES  800000
#define E4       (N_EDGES / 4)  // 200000
#define KTOT     (N_REL * IN_F) // 1024
#define NBLK     196            // ceil(N_NODES/256) scan blocks per relation
#define CAP      64             // fallback per-node bucket cap

typedef unsigned short ushort_t;
typedef __attribute__((ext_vector_type(8))) short short8;
typedef __attribute__((ext_vector_type(4))) float f32x4;
typedef __attribute__((ext_vector_type(4))) int  int4v;

__device__ inline ushort_t f2bf(float f) {
    unsigned u = __float_as_uint(f);
    return (ushort_t)((u + 0x7fffu + ((u >> 16) & 1u)) >> 16);   // RNE
}
__device__ inline float bflo(unsigned v) { return __uint_as_float(v << 16); }
__device__ inline float bfhi(unsigned v) { return __uint_as_float(v & 0xffff0000u); }

// BT[o][r*128+i] = sum_b w_comp[r,b]*weight[b,i,o]  (bf16, B^T layout for MFMA)
__global__ __launch_bounds__(256) void compute_ws_bt_kernel(
    const float* __restrict__ weight,
    const float* __restrict__ w_comp,
    ushort_t* __restrict__ BT)
{
    int idx = blockIdx.x * 256 + threadIdx.x;        // over 128*1024
    if (idx >= OUT_F * KTOT) return;
    int o  = idx >> 10;
    int ri = idx & 1023;
    int r  = ri >> 7;
    int i  = ri & 127;
    float acc = 0.f;
#pragma unroll
    for (int b = 0; b < N_BASES; ++b)
        acc += w_comp[r * N_BASES + b] * weight[b * (IN_F * OUT_F) + i * OUT_F + o];
    BT[idx] = f2bf(acc);
}

// x (f32) -> xb (bf16 pairs): xb dword k of a row = bf16(feat 2k) | bf16(feat 2k+1)<<16
__global__ __launch_bounds__(256) void x2bf_kernel(
    const float4* __restrict__ x4, uint2* __restrict__ xb)
{
    int i = blockIdx.x * 256 + threadIdx.x;
    if (i >= N_NODES * IN_F / 4) return;
    float4 v = x4[i];
    uint2 p;
    p.x = (unsigned)f2bf(v.x) | ((unsigned)f2bf(v.y) << 16);
    p.y = (unsigned)f2bf(v.z) | ((unsigned)f2bf(v.w) << 16);
    xb[i] = p;
}

// Pass 1: per-relation degree histogram. XCD-sharded (r = bid&7) so each
// relation's 200 KB counter region stays in one XCD's L2.
__global__ __launch_bounds__(256) void hist_kernel(
    const int4v* __restrict__ dst4, int* __restrict__ cnt)
{
    int r  = blockIdx.x & 7;
    int cb = blockIdx.x >> 3;                         // 0..255
    const int4v* d4 = dst4 + (size_t)r * E4;
    int base = r * N_NODES;
    for (int i = cb * 256 + (int)threadIdx.x; i < E4; i += 256 * 256) {
        int4v d = __builtin_nontemporal_load(&d4[i]);
        atomicAdd(&cnt[base + d.x], 1);
        atomicAdd(&cnt[base + d.y], 1);
        atomicAdd(&cnt[base + d.z], 1);
        atomicAdd(&cnt[base + d.w], 1);
    }
}

// Scan step 1: per-256-node block sums.  grid = 8*NBLK, bsum[bid] = sum.
__global__ __launch_bounds__(256) void scan_bsum_kernel(
    const int* __restrict__ cnt, int* __restrict__ bsum)
{
    __shared__ int sm[256];
    int r = blockIdx.x / NBLK;
    int b = blockIdx.x % NBLK;
    int n = b * 256 + threadIdx.x;
    sm[threadIdx.x] = (n < N_NODES) ? cnt[r * N_NODES + n] : 0;
    __syncthreads();
    for (int s = 128; s > 0; s >>= 1) {
        if ((int)threadIdx.x < s) sm[threadIdx.x] += sm[threadIdx.x + s];
        __syncthreads();
    }
    if (threadIdx.x == 0) bsum[blockIdx.x] = sm[0];
}

// Scan step 2: serial exclusive scan of NBLK block sums per relation (8 lanes).
__global__ __launch_bounds__(64) void scan_relbase_kernel(int* __restrict__ bsum)
{
    int r = threadIdx.x;
    if (r >= N_REL) return;
    int run = 0;
    for (int i = 0; i < NBLK; ++i) {
        int t = bsum[r * NBLK + i];
        bsum[r * NBLK + i] = run;
        run += t;
    }
}

// Scan step 3: block-local exclusive scan + block base -> start offsets.
__global__ __launch_bounds__(256) void scan_start_kernel(
    const int* __restrict__ cnt, const int* __restrict__ bsum,
    int* __restrict__ start)
{
    __shared__ int sm[256];
    int r = blockIdx.x / NBLK;
    int b = blockIdx.x % NBLK;
    int n = b * 256 + threadIdx.x;
    int v = (n < N_NODES) ? cnt[r * N_NODES + n] : 0;
    sm[threadIdx.x] = v;
    __syncthreads();
    for (int off = 1; off < 256; off <<= 1) {
        int t = ((int)threadIdx.x >= off) ? sm[threadIdx.x - off] : 0;
        __syncthreads();
        sm[threadIdx.x] += t;
        __syncthreads();
    }
    if (n < N_NODES)
        start[r * N_NODES + n] = sm[threadIdx.x] - v + bsum[blockIdx.x];
}

// Pass 2: place src ids into compact CSR edge array (1.6 MB/relation ->
// L2-resident with XCD sharding; full-line writebacks).
__global__ __launch_bounds__(256) void place_kernel(
    const int4v* __restrict__ src4,
    const int4v* __restrict__ dst4,
    const int* __restrict__ start,
    int* __restrict__ fill,
    ushort_t* __restrict__ earr)
{
    int r  = blockIdx.x & 7;
    int cb = blockIdx.x >> 3;
    const int4v* s4 = src4 + (size_t)r * E4;
    const int4v* d4 = dst4 + (size_t)r * E4;
    int base = r * N_NODES;
    ushort_t* er = earr + (size_t)r * N_EDGES;
    for (int i = cb * 256 + (int)threadIdx.x; i < E4; i += 256 * 256) {
        int4v s = __builtin_nontemporal_load(&s4[i]);
        int4v d = __builtin_nontemporal_load(&d4[i]);
#define PUT(DV, SV) { int sl = base + (DV);                                   \
        int pos = atomicAdd(&fill[sl], 1);                                    \
        er[start[sl] + pos] = (ushort_t)(SV); }
        PUT(d.x, s.x) PUT(d.y, s.y) PUT(d.z, s.z) PUT(d.w, s.w)
#undef PUT
    }
}

// One wave per (relation, node), relation = bid&7. Chunked over full degree
// (exact CSR, no cap). Reads bf16 x rows (256B), writes bf16 mean row of A.
__global__ __launch_bounds__(256) void gather_csr_kernel(
    const unsigned* __restrict__ xb,   // [N][64] dwords
    const int* __restrict__ cnt,
    const int* __restrict__ start,
    const ushort_t* __restrict__ earr,
    ushort_t* __restrict__ A)          // [NPAD][KTOT]
{
    int r = blockIdx.x & 7;
    int n = (blockIdx.x >> 3) * 4 + ((int)threadIdx.x >> 6);
    int lane = threadIdx.x & 63;
    int slot = r * N_NODES + n;
    int c = cnt[slot];
    const ushort_t* ep = earr + (size_t)r * N_EDGES + start[slot];

    float ax = 0.f, ay = 0.f, bx = 0.f, by = 0.f;
    for (int base = 0; base < c; base += 64) {
        int m = min(c - base, 64);
        int sid = (lane < m) ? (int)ep[base + lane] : 0;
        int e = 0;
        for (; e + 2 <= m; e += 2) {
            int s0 = __shfl(sid, e);
            int s1 = __shfl(sid, e + 1);
            unsigned v0 = xb[(size_t)s0 * 64 + lane];
            unsigned v1 = xb[(size_t)s1 * 64 + lane];
            ax += bflo(v0); ay += bfhi(v0);
            bx += bflo(v1); by += bfhi(v1);
        }
        if (e < m) {
            int s0 = __shfl(sid, e);
            unsigned v0 = xb[(size_t)s0 * 64 + lane];
            ax += bflo(v0); ay += bfhi(v0);
        }
    }
    const float inv = 1.0f / fmaxf((float)c, 1.0f);
    unsigned lo = f2bf((ax + bx) * inv);
    unsigned hi = f2bf((ay + by) * inv);
    ((unsigned*)(A + (size_t)n * KTOT + r * IN_F))[lane] = lo | (hi << 16);
}

// ---------------- fallback-path kernels (small workspace) ----------------
__global__ __launch_bounds__(256) void bucket_fill_kernel(
    const int* __restrict__ src,
    const int* __restrict__ dst,
    int* __restrict__ cnt,
    ushort_t* __restrict__ bucket,
    int nedges)
{
    int e = blockIdx.x * 256 + threadIdx.x;
    if (e >= nedges) return;
    int d = dst[e];
    int pos = atomicAdd(&cnt[d], 1);
    if (pos < CAP)
        bucket[(size_t)d * CAP + pos] = (ushort_t)src[e];
}

__global__ __launch_bounds__(256) void gather_mean_fb_kernel(
    const float* __restrict__ x,
    const int* __restrict__ cnt,
    const ushort_t* __restrict__ bucket,
    ushort_t* __restrict__ A)
{
    int wv = (blockIdx.x * 256 + threadIdx.x) >> 6;
    if (wv >= N_NODES) return;
    int lane = threadIdx.x & 63;
    int c  = cnt[wv];
    int cc = min(c, CAP);
    int sid = (lane < cc) ? (int)bucket[(size_t)wv * CAP + lane] : 0;

    float ax = 0.f, ay = 0.f, bx = 0.f, by = 0.f;
    int e = 0;
    for (; e + 2 <= cc; e += 2) {
        int s0 = __shfl(sid, e);
        int s1 = __shfl(sid, e + 1);
        const float2 v0 = *(const float2*)(x + (size_t)s0 * IN_F + lane * 2);
        const float2 v1 = *(const float2*)(x + (size_t)s1 * IN_F + lane * 2);
        ax += v0.x; ay += v0.y;
        bx += v1.x; by += v1.y;
    }
    if (e < cc) {
        int s0 = __shfl(sid, e);
        const float2 v0 = *(const float2*)(x + (size_t)s0 * IN_F + lane * 2);
        ax += v0.x; ay += v0.y;
    }
    const float inv = 1.0f / fmaxf((float)c, 1.0f);
    unsigned lo = f2bf((ax + bx) * inv);
    unsigned hi = f2bf((ay + by) * inv);
    ((unsigned*)(A + (size_t)wv * IN_F))[lane] = lo | (hi << 16);
}

// C[rows x 128] (+)= A[rows x K]_bf16 @ B (BT stored [128][KTOT]).
// Block 256 = 4 waves; block tile 64 rows x 128 cols; wave = 32 rows x 64 cols.
__global__ __launch_bounds__(256) void gemm_mfma_kernel(
    const ushort_t* __restrict__ A, int lda,
    const ushort_t* __restrict__ BT, int kbase, int K,
    float* __restrict__ out, const float* __restrict__ bias,
    int first, int last)
{
    int tid  = threadIdx.x;
    int wave = tid >> 6, lane = tid & 63;
    int rowf = lane & 15, kg = lane >> 4;
    int rbase = blockIdx.x * 64 + (wave & 1) * 32;
    int cbase = (wave >> 1) * 64;

    f32x4 acc[2][4];
#pragma unroll
    for (int t = 0; t < 2; ++t)
#pragma unroll
        for (int c = 0; c < 4; ++c) acc[t][c] = (f32x4){0.f, 0.f, 0.f, 0.f};

    const ushort_t* Arow0 = A + (size_t)(rbase + rowf) * lda;
    const ushort_t* Arow1 = A + (size_t)(rbase + 16 + rowf) * lda;
    const ushort_t* Bbase = BT + (size_t)(cbase + rowf) * KTOT + kbase;

    for (int k0 = 0; k0 < K; k0 += 32) {
        int kk = k0 + kg * 8;
        short8 a0 = *(const short8*)(Arow0 + kk);
        short8 a1 = *(const short8*)(Arow1 + kk);
#pragma unroll
        for (int c = 0; c < 4; ++c) {
            short8 b = *(const short8*)(Bbase + c * 16 * KTOT + kk);
            acc[0][c] = __builtin_amdgcn_mfma_f32_16x16x32_bf16(a0, b, acc[0][c], 0, 0, 0);
            acc[1][c] = __builtin_amdgcn_mfma_f32_16x16x32_bf16(a1, b, acc[1][c], 0, 0, 0);
        }
    }

    // C/D layout: col = lane&15, row = (lane>>4)*4 + j
#pragma unroll
    for (int t = 0; t < 2; ++t) {
#pragma unroll
        for (int c = 0; c < 4; ++c) {
            int col = cbase + c * 16 + rowf;
#pragma unroll
            for (int j = 0; j < 4; ++j) {
                int row = rbase + t * 16 + kg * 4 + j;
                if (row < N_NODES) {
                    float v = acc[t][c][j];
                    float* p = out + (size_t)row * OUT_F + col;
                    if (!first) v += *p;
                    if (last)  v = fmaxf(v + bias[col], 0.f);
                    *p = v;
                }
            }
        }
    }
}

extern "C" void kernel_launch(void* const* d_in, const int* in_sizes, int n_in,
                              void* d_out, int out_size, void* d_ws, size_t ws_size,
                              hipStream_t stream) {
    const float* x      = (const float*)d_in[0];
    const float* weight = (const float*)d_in[1];
    const float* w_comp = (const float*)d_in[2];
    const float* h_bias = (const float*)d_in[3];
    const int*   src    = (const int*)d_in[4];
    const int*   dst    = (const int*)d_in[5];
    float* out = (float*)d_out;

    char* wsb = (char*)d_ws;
    const size_t btSz   = (size_t)OUT_F * KTOT * 2;            // 256 KB
    const size_t cntSz  = (size_t)N_REL * N_NODES * 4;         // 1.6 MB
    const size_t bsumSz = (size_t)8192;                        // 1568*4 padded
    const size_t earrSz = (size_t)N_REL * N_EDGES * 2;         // 12.8 MB
    const size_t aSz    = (size_t)NPAD * KTOT * 2;             // 102.5 MB
    const size_t xbSz   = (size_t)N_NODES * 64 * 4;            // 12.8 MB
    const size_t need   = btSz + 3 * cntSz + bsumSz + earrSz + aSz + xbSz; // ~133 MB

    ushort_t* BT = (ushort_t*)wsb;
    compute_ws_bt_kernel<<<(OUT_F * KTOT + 255) / 256, 256, 0, stream>>>(
        weight, w_comp, BT);

    if (ws_size >= need) {
        int*      cnt   = (int*)(wsb + btSz);
        int*      fill  = (int*)(wsb + btSz + cntSz);
        int*      start = (int*)(wsb + btSz + 2 * cntSz);
        int*      bsum  = (int*)(wsb + btSz + 3 * cntSz);
        ushort_t* earr  = (ushort_t*)(wsb + btSz + 3 * cntSz + bsumSz);
        ushort_t* A     = (ushort_t*)(wsb + btSz + 3 * cntSz + bsumSz + earrSz);
        unsigned* xb    = (unsigned*)(wsb + btSz + 3 * cntSz + bsumSz + earrSz + aSz);

        x2bf_kernel<<<(N_NODES * IN_F / 4 + 255) / 256, 256, 0, stream>>>(
            (const float4*)x, (uint2*)xb);
        hipMemsetAsync(cnt, 0, 2 * cntSz, stream);   // cnt + fill
        hist_kernel<<<8 * 256, 256, 0, stream>>>((const int4v*)dst, cnt);
        scan_bsum_kernel<<<N_REL * NBLK, 256, 0, stream>>>(cnt, bsum);
        scan_relbase_kernel<<<1, 64, 0, stream>>>(bsum);
        scan_start_kernel<<<N_REL * NBLK, 256, 0, stream>>>(cnt, bsum, start);
        place_kernel<<<8 * 256, 256, 0, stream>>>(
            (const int4v*)src, (const int4v*)dst, start, fill, earr);
        gather_csr_kernel<<<8 * (N_NODES / 4), 256, 0, stream>>>(
            xb, cnt, start, earr, A);
        gemm_mfma_kernel<<<NPAD / 64, 256, 0, stream>>>(
            A, KTOT, BT, 0, KTOT, out, h_bias, 1, 1);
    } else {
        // per-relation fallback (~19.7 MB)
        const size_t cntSz1 = (size_t)N_NODES * 4;
        const size_t bktSz1 = (size_t)N_NODES * CAP * 2;
        int*      cnt    = (int*)(wsb + btSz);
        ushort_t* bucket = (ushort_t*)(wsb + btSz + cntSz1);
        ushort_t* A      = (ushort_t*)(wsb + btSz + cntSz1 + bktSz1);

        for (int r = 0; r < N_REL; ++r) {
            hipMemsetAsync(cnt, 0, cntSz1, stream);
            bucket_fill_kernel<<<(N_EDGES + 255) / 256, 256, 0, stream>>>(
                src + (size_t)r * N_EDGES, dst + (size_t)r * N_EDGES,
                cnt, bucket, N_EDGES);
            gather_mean_fb_kernel<<<(N_NODES * 64 + 255) / 256, 256, 0, stream>>>(
                x, cnt, bucket, A);
            gemm_mfma_kernel<<<NPAD / 64, 256, 0, stream>>>(
                A, IN_F, BT, r * IN_F, IN_F, out, h_bias,
                r == 0, r == N_REL - 1);
        }
    }
}